// Round 5
// baseline (67.271 us; speedup 1.0000x reference)
//
#include <hip/hip_runtime.h>
#include <stdint.h>

#define NB 32
#define NM 64
#define NPM 144
#define NPF 128
#define NCMS 8
#define NNEUR 16
#define NOUT 128
#define RMAX 256
#define NC 16  // r-chunks per m in k_gather
#define CLEN_MAX 32

// ---- Threefry-2x32, key = (0, 42)  (jax.random.key(42)) ----
__device__ __forceinline__ uint32_t rotl32(uint32_t x, int d) {
  return (x << d) | (x >> (32 - d));
}

__device__ __forceinline__ void threefry2x32(uint32_t& x0, uint32_t& x1) {
  const uint32_t k0 = 0u, k1 = 42u;
  const uint32_t k2 = 0x1BD11BDAu ^ k0 ^ k1;
  x0 += k0; x1 += k1;
#define TF_R(r) { x0 += x1; x1 = rotl32(x1, (r)); x1 ^= x0; }
  TF_R(13) TF_R(15) TF_R(26) TF_R(6)  x0 += k1; x1 += k2 + 1u;
  TF_R(17) TF_R(29) TF_R(16) TF_R(24) x0 += k2; x1 += k0 + 2u;
  TF_R(13) TF_R(15) TF_R(26) TF_R(6)  x0 += k0; x1 += k1 + 3u;
  TF_R(17) TF_R(29) TF_R(16) TF_R(24) x0 += k1; x1 += k2 + 4u;
  TF_R(13) TF_R(15) TF_R(26) TF_R(6)  x0 += k2; x1 += k0 + 5u;
#undef TF_R
}

// partitionable threefry: bits[i] = o0 ^ o1 of threefry(hi32(i)=0, lo32(i)=i)
__device__ __forceinline__ float gumbel_at(uint32_t idx) {
  uint32_t x0 = 0u, x1 = idx;
  threefry2x32(x0, x1);
  uint32_t bits = x0 ^ x1;
  float f = __uint_as_float((bits >> 9) | 0x3f800000u) - 1.0f;
  float u = fmaxf(f, 1.17549435e-38f);
  return -logf(-logf(u));
}

// ---- k1: winner extraction. win[pm][cm][b] (byte), 144*8*32 = 36864 B ----
__global__ __launch_bounds__(128) void k_winners(const float* __restrict__ x,
                                                 unsigned char* __restrict__ win) {
  const int pm = blockIdx.x;
  const int b0 = blockIdx.y * 8;
  const int tid = threadIdx.x;
  const int grp = tid >> 4, lane16 = tid & 15;
#pragma unroll
  for (int i = 0; i < 8; ++i) {
    int b = b0 + i;
    float xv = x[((size_t)b * NPM + pm) * NPF + tid];
    unsigned long long msk = __ballot(xv > 0.5f);
    int base = (tid & 63) & ~15;
    int wv = __builtin_ctzll((msk >> base) & 0xFFFFull);
    if (lane16 == 0) win[pm * 256 + grp * 32 + b] = (unsigned char)wv;
  }
}

// ---- k2: cross-batch gather-accumulate into partials[c][m][b][o] (f32) ----
// 256 threads: oq = tid&31 (4 outputs), bg = tid>>5 (4 batches); 2-cm unroll
__global__ __launch_bounds__(256) void k_gather(
    const float* __restrict__ w, const int* __restrict__ conns,
    const unsigned char* __restrict__ win, float* __restrict__ part, int R) {
  const int bid = blockIdx.x;
  const int m = (bid * 21) & 63;  // scrambled: decorrelate RF size across CUs
  const int c = bid >> 6;
  const int tid = threadIdx.x;
  const int oq4 = (tid & 31) << 2;  // o-quad float offset
  const int bg = tid >> 5;          // batch group: b = bg*4 .. bg*4+3

  __shared__ int s_conn[CLEN_MAX];
  __shared__ unsigned char s_winb[CLEN_MAX * 256];  // [rr][cm][b]

  // nvalid (valid conns are contiguous at the front)
  int nv = 0;
  for (int base = 0; base < R; base += 256) {
    int r = base + tid;
    int pmv = (r < R) ? conns[m * R + r] : NPM;
    nv += __syncthreads_count(pmv != NPM);
  }
  const int s = (nv * c) / NC, e = (nv * (c + 1)) / NC;
  const int clen = e - s;

  if (tid < clen) s_conn[tid] = conns[m * R + s + tid];
  __syncthreads();
  for (int idx = tid; idx < clen * 256; idx += 256) {
    int rr = idx >> 8;
    s_winb[idx] = win[s_conn[rr] * 256 + (idx & 255)];
  }
  __syncthreads();

  const float* wbase =
      w + (size_t)m * ((size_t)R * NPF * NOUT) + ((size_t)s << 14);

  float facc[4][4] = {};
  double dacc[4][4] = {};

  for (int rr = 0; rr < clen; ++rr) {
    const float* wr = wbase + ((size_t)rr << 14);
    const uint32_t* wrow = (const uint32_t*)&s_winb[rr << 8];
#pragma unroll
    for (int cmo = 0; cmo < 4; ++cmo) {
      const int cm = cmo << 1;
      const uint32_t w4a = wrow[(cm << 3) + bg];
      const uint32_t w4b = wrow[((cm + 1) << 3) + bg];
      const float* wca = wr + (cm << 11);
      const float* wcb = wca + (1 << 11);
      float4 va[4], vb[4];
#pragma unroll
      for (int bb = 0; bb < 4; ++bb) {
        int row = (int)((w4a >> (bb * 8)) & 15);
        va[bb] = *(const float4*)(wca + (row << 7) + oq4);
      }
#pragma unroll
      for (int bb = 0; bb < 4; ++bb) {
        int row = (int)((w4b >> (bb * 8)) & 15);
        vb[bb] = *(const float4*)(wcb + (row << 7) + oq4);
      }
#pragma unroll
      for (int bb = 0; bb < 4; ++bb) {
        facc[bb][0] += va[bb].x; facc[bb][1] += va[bb].y;
        facc[bb][2] += va[bb].z; facc[bb][3] += va[bb].w;
        facc[bb][0] += vb[bb].x; facc[bb][1] += vb[bb].y;
        facc[bb][2] += vb[bb].z; facc[bb][3] += vb[bb].w;
      }
    }
    // flush per-rr sub-sum (8 fp32 adds deep, cm-ascending) into fp64
#pragma unroll
    for (int bb = 0; bb < 4; ++bb) {
#pragma unroll
      for (int k = 0; k < 4; ++k) {
        dacc[bb][k] += (double)facc[bb][k];
        facc[bb][k] = 0.0f;
      }
    }
  }

  float* pb = part + ((size_t)c * NM + m) * NB * NOUT;
#pragma unroll
  for (int bb = 0; bb < 4; ++bb) {
    float4 v;
    v.x = (float)dacc[bb][0]; v.y = (float)dacc[bb][1];
    v.z = (float)dacc[bb][2]; v.w = (float)dacc[bb][3];
    *(float4*)(pb + (size_t)((bg << 2) + bb) * NOUT + oq4) = v;
  }
}

// ---- k3: reduce partials + epilogue (softmax/gumbel/argmax) ----
__global__ __launch_bounds__(128) void k_epilogue(
    const float* __restrict__ part, const int* __restrict__ conns,
    const float* __restrict__ thr_min, const float* __restrict__ thr_max,
    float* __restrict__ out, int R) {
  const int tid = threadIdx.x;
  const int m = blockIdx.x >> 5, b = blockIdx.x & 31;
  const int grp = tid >> 4, lane16 = tid & 15;
  __shared__ float s_red[8];

  int nv = 0;
  for (int base = 0; base < R; base += 128) {
    int r = base + tid;
    int pmv = (r < R) ? conns[m * R + r] : NPM;
    nv += __syncthreads_count(pmv != NPM);
  }

  double acc = 0.0;
#pragma unroll
  for (int c = 0; c < NC; ++c)
    acc += (double)part[(((size_t)c * NM + m) * NB + b) * NOUT + tid];

  float sums = 8.0f * (float)nv;
  float h = (float)acc / fmaxf(sums, 1.0f);

  float hm = h;
#pragma unroll
  for (int off = 8; off >= 1; off >>= 1) hm = fmaxf(hm, __shfl_xor(hm, off, 16));
  if (lane16 == 0) s_red[grp] = hm;
  __syncthreads();
  float fam = s_red[0];
#pragma unroll
  for (int cc = 1; cc < 8; ++cc) fam += s_red[cc];
  fam *= 0.125f;

  float eta = 2.5f / (1.0f + expf(-28.0f * (fam - 0.5f)));
  if (!(fam >= 0.2f)) eta = 0.0f;

  float v = eta * h;
  float vm = v;
#pragma unroll
  for (int off = 8; off >= 1; off >>= 1) vm = fmaxf(vm, __shfl_xor(vm, off, 16));
  float ee = expf(v - vm);
  float ss = ee;
#pragma unroll
  for (int off = 8; off >= 1; off >>= 1) ss += __shfl_xor(ss, off, 16);
  float p = ee / ss;

  uint32_t idx = (uint32_t)(((b * NM + m) * NCMS + grp) * NNEUR + lane16);
  float y = logf(p + 1e-30f) + gumbel_at(idx);

  float bv = y;
  int bi = lane16;
#pragma unroll
  for (int off = 8; off >= 1; off >>= 1) {
    float ov = __shfl_xor(bv, off, 16);
    int oi = __shfl_xor(bi, off, 16);
    if (ov > bv || (ov == bv && oi < bi)) { bv = ov; bi = oi; }
  }

  float act = (sums >= thr_min[m] && sums <= thr_max[m]) ? 1.0f : 0.0f;
  out[(size_t)(b * NM + m) * NOUT + tid] = (lane16 == bi) ? act : 0.0f;
}

// ---- fallback: round-0 single kernel (used only if d_ws is too small) ----
__global__ __launch_bounds__(128) void sparsey_fallback(
    const float* __restrict__ x, const float* __restrict__ w,
    const int* __restrict__ conns, const float* __restrict__ thr_min,
    const float* __restrict__ thr_max, float* __restrict__ out, int R) {
  const int tid = threadIdx.x;
  const int bid = blockIdx.x;
  const int m = bid >> 5;
  const int b = bid & 31;

  __shared__ int s_conn[RMAX];
  __shared__ unsigned char s_win[RMAX * 8];
  __shared__ float s_red[8];

  for (int r = tid; r < R; r += 128) s_conn[r] = conns[m * R + r];
  __syncthreads();

  const int grp = tid >> 4;
  const int lane16 = tid & 15;

  int nvalid = 0;
  const float* xb = x + (size_t)b * (NPM * NPF);
  for (int r = 0; r < R; ++r) {
    int pm = s_conn[r];
    if (pm == NPM) continue;
    ++nvalid;
    float xv = xb[(size_t)pm * NPF + tid];
    unsigned long long msk = __ballot(xv > 0.5f);
    int base = (tid & 63) & ~15;
    int wv = __builtin_ctzll((msk >> base) & 0xFFFFull);
    if (lane16 == 0) s_win[r * 8 + grp] = (unsigned char)wv;
  }
  __syncthreads();

  double acc = 0.0;
  const float* wm = w + (size_t)m * ((size_t)R * NPF * NOUT);
  for (int r = 0; r < R; ++r) {
    if (s_conn[r] == NPM) continue;
    const float* wr = wm + (size_t)r * (NPF * NOUT);
#pragma unroll
    for (int cm = 0; cm < 8; ++cm) {
      int row = cm * 16 + (int)s_win[r * 8 + cm];
      acc += (double)wr[row * NOUT + tid];
    }
  }

  float sums = 8.0f * (float)nvalid;
  float h = (float)acc / fmaxf(sums, 1.0f);

  float hm = h;
#pragma unroll
  for (int off = 8; off >= 1; off >>= 1) hm = fmaxf(hm, __shfl_xor(hm, off, 16));
  if (lane16 == 0) s_red[grp] = hm;
  __syncthreads();
  float fam = s_red[0];
#pragma unroll
  for (int c = 1; c < 8; ++c) fam += s_red[c];
  fam *= 0.125f;

  float eta = 2.5f / (1.0f + expf(-28.0f * (fam - 0.5f)));
  if (!(fam >= 0.2f)) eta = 0.0f;

  float v = eta * h;
  float vm = v;
#pragma unroll
  for (int off = 8; off >= 1; off >>= 1) vm = fmaxf(vm, __shfl_xor(vm, off, 16));
  float e = expf(v - vm);
  float ssum = e;
#pragma unroll
  for (int off = 8; off >= 1; off >>= 1) ssum += __shfl_xor(ssum, off, 16);
  float p = e / ssum;

  uint32_t idx = (uint32_t)(((b * NM + m) * NCMS + grp) * NNEUR + lane16);
  float y = logf(p + 1e-30f) + gumbel_at(idx);

  float bv = y;
  int bi = lane16;
#pragma unroll
  for (int off = 8; off >= 1; off >>= 1) {
    float ov = __shfl_xor(bv, off, 16);
    int oi = __shfl_xor(bi, off, 16);
    if (ov > bv || (ov == bv && oi < bi)) { bv = ov; bi = oi; }
  }

  float act = (sums >= thr_min[m] && sums <= thr_max[m]) ? 1.0f : 0.0f;
  out[(size_t)(b * NM + m) * NOUT + tid] = (lane16 == bi) ? act : 0.0f;
}

extern "C" void kernel_launch(void* const* d_in, const int* in_sizes, int n_in,
                              void* d_out, int out_size, void* d_ws, size_t ws_size,
                              hipStream_t stream) {
  const float* x = (const float*)d_in[0];
  const float* w = (const float*)d_in[1];
  const int* conns = (const int*)d_in[2];
  const float* tmin = (const float*)d_in[3];
  const float* tmax = (const float*)d_in[4];
  float* out = (float*)d_out;

  const int R = in_sizes[2] / NM;

  const size_t WIN_BYTES = 65536;  // 36864 used, pad to 64K for alignment
  const size_t PART_BYTES = (size_t)NC * NM * NB * NOUT * sizeof(float);

  if (ws_size < WIN_BYTES + PART_BYTES || R > RMAX || R > CLEN_MAX * NC) {
    sparsey_fallback<<<dim3(NM * NB), 128, 0, stream>>>(x, w, conns, tmin, tmax,
                                                        out, R);
    return;
  }

  unsigned char* win = (unsigned char*)d_ws;
  float* part = (float*)((char*)d_ws + WIN_BYTES);

  k_winners<<<dim3(NPM, 4), 128, 0, stream>>>(x, win);
  k_gather<<<dim3(NM * NC), 256, 0, stream>>>(w, conns, win, part, R);
  k_epilogue<<<dim3(NM * NB), 128, 0, stream>>>(part, conns, tmin, tmax, out, R);
}

// Round 6
// 61.656 us; speedup vs baseline: 1.0911x; 1.0911x over previous
//
#include <hip/hip_runtime.h>
#include <stdint.h>

#define NB 32
#define NM 64
#define NPM 144
#define NPF 128
#define NCMS 8
#define NNEUR 16
#define NOUT 128
#define RMAX 256
#define NC 16  // r-chunks per m in k_gather
#define CLEN_MAX 32

// ---- Threefry-2x32, key = (0, 42)  (jax.random.key(42)) ----
__device__ __forceinline__ uint32_t rotl32(uint32_t x, int d) {
  return (x << d) | (x >> (32 - d));
}

__device__ __forceinline__ void threefry2x32(uint32_t& x0, uint32_t& x1) {
  const uint32_t k0 = 0u, k1 = 42u;
  const uint32_t k2 = 0x1BD11BDAu ^ k0 ^ k1;
  x0 += k0; x1 += k1;
#define TF_R(r) { x0 += x1; x1 = rotl32(x1, (r)); x1 ^= x0; }
  TF_R(13) TF_R(15) TF_R(26) TF_R(6)  x0 += k1; x1 += k2 + 1u;
  TF_R(17) TF_R(29) TF_R(16) TF_R(24) x0 += k2; x1 += k0 + 2u;
  TF_R(13) TF_R(15) TF_R(26) TF_R(6)  x0 += k0; x1 += k1 + 3u;
  TF_R(17) TF_R(29) TF_R(16) TF_R(24) x0 += k1; x1 += k2 + 4u;
  TF_R(13) TF_R(15) TF_R(26) TF_R(6)  x0 += k2; x1 += k0 + 5u;
#undef TF_R
}

// partitionable threefry: bits[i] = o0 ^ o1 of threefry(hi32(i)=0, lo32(i)=i)
__device__ __forceinline__ float gumbel_at(uint32_t idx) {
  uint32_t x0 = 0u, x1 = idx;
  threefry2x32(x0, x1);
  uint32_t bits = x0 ^ x1;
  float f = __uint_as_float((bits >> 9) | 0x3f800000u) - 1.0f;
  float u = fmaxf(f, 1.17549435e-38f);
  return -logf(-logf(u));
}

// ---- k1: winner extraction. win[pm][cm][b] (byte), 144*8*32 = 36864 B ----
__global__ __launch_bounds__(128) void k_winners(const float* __restrict__ x,
                                                 unsigned char* __restrict__ win) {
  const int pm = blockIdx.x;
  const int b0 = blockIdx.y * 8;
  const int tid = threadIdx.x;
  const int grp = tid >> 4, lane16 = tid & 15;
#pragma unroll
  for (int i = 0; i < 8; ++i) {
    int b = b0 + i;
    float xv = x[((size_t)b * NPM + pm) * NPF + tid];
    unsigned long long msk = __ballot(xv > 0.5f);
    int base = (tid & 63) & ~15;
    int wv = __builtin_ctzll((msk >> base) & 0xFFFFull);
    if (lane16 == 0) win[pm * 256 + grp * 32 + b] = (unsigned char)wv;
  }
}

// ---- k2: cross-batch gather-accumulate into partials[c][m][b][o] (f32) ----
__global__ __launch_bounds__(256) void k_gather(
    const float* __restrict__ w, const int* __restrict__ conns,
    const unsigned char* __restrict__ win, float* __restrict__ part, int R) {
  const int bid = blockIdx.x;
  const int m = (bid * 21) & 63;  // scrambled: decorrelate RF size across CUs
  const int c = bid >> 6;
  const int tid = threadIdx.x;
  const int oq = tid & 31;   // o-quad: o = oq*4 .. oq*4+3
  const int bg = tid >> 5;   // batch group: b = bg*4 .. bg*4+3

  __shared__ int s_conn[CLEN_MAX];
  __shared__ unsigned char s_winb[CLEN_MAX * 256];  // [rr][cm][b]

  // nvalid (valid conns are contiguous at the front)
  int nv = 0;
  for (int base = 0; base < R; base += 256) {
    int r = base + tid;
    int pmv = (r < R) ? conns[m * R + r] : NPM;
    nv += __syncthreads_count(pmv != NPM);
  }
  const int s = (nv * c) / NC, e = (nv * (c + 1)) / NC;
  const int clen = e - s;

  if (tid < clen) s_conn[tid] = conns[m * R + s + tid];
  __syncthreads();
  for (int idx = tid; idx < clen * 256; idx += 256) {
    int rr = idx >> 8;
    s_winb[idx] = win[s_conn[rr] * 256 + (idx & 255)];
  }
  __syncthreads();

  const float* wm = w + (size_t)m * ((size_t)R * NPF * NOUT);

  float facc[4][4] = {};
  double dacc[4][4] = {};

  const int n = clen * 8;
  for (int it = 0; it < n; ++it) {
    const int rr = it >> 3, cm = it & 7;
    const uint32_t w4 =
        *(const uint32_t*)&s_winb[(rr << 8) + (cm << 5) + (bg << 2)];
    const float* wp = wm + (((size_t)(s + rr) * NPF + (cm << 4)) << 7);
#pragma unroll
    for (int bb = 0; bb < 4; ++bb) {
      int row = (w4 >> (bb * 8)) & 15;
      const float4 v = *(const float4*)(wp + (row << 7) + (oq << 2));
      facc[bb][0] += v.x; facc[bb][1] += v.y;
      facc[bb][2] += v.z; facc[bb][3] += v.w;
    }
    if ((it & 7) == 7) {  // flush per-r sub-sum (8 adds) into fp64
#pragma unroll
      for (int bb = 0; bb < 4; ++bb) {
#pragma unroll
        for (int k = 0; k < 4; ++k) {
          dacc[bb][k] += (double)facc[bb][k];
          facc[bb][k] = 0.0f;
        }
      }
    }
  }

  float* pb = part + ((size_t)c * NM + m) * NB * NOUT;
#pragma unroll
  for (int bb = 0; bb < 4; ++bb) {
    float4 v;
    v.x = (float)dacc[bb][0]; v.y = (float)dacc[bb][1];
    v.z = (float)dacc[bb][2]; v.w = (float)dacc[bb][3];
    *(float4*)(pb + (size_t)(bg * 4 + bb) * NOUT + (oq << 2)) = v;
  }
}

// ---- k3: reduce partials + epilogue (softmax/gumbel/argmax) ----
__global__ __launch_bounds__(128) void k_epilogue(
    const float* __restrict__ part, const int* __restrict__ conns,
    const float* __restrict__ thr_min, const float* __restrict__ thr_max,
    float* __restrict__ out, int R) {
  const int tid = threadIdx.x;
  const int m = blockIdx.x >> 5, b = blockIdx.x & 31;
  const int grp = tid >> 4, lane16 = tid & 15;
  __shared__ float s_red[8];

  int nv = 0;
  for (int base = 0; base < R; base += 128) {
    int r = base + tid;
    int pmv = (r < R) ? conns[m * R + r] : NPM;
    nv += __syncthreads_count(pmv != NPM);
  }

  double acc = 0.0;
#pragma unroll
  for (int c = 0; c < NC; ++c)
    acc += (double)part[(((size_t)c * NM + m) * NB + b) * NOUT + tid];

  float sums = 8.0f * (float)nv;
  float h = (float)acc / fmaxf(sums, 1.0f);

  float hm = h;
#pragma unroll
  for (int off = 8; off >= 1; off >>= 1) hm = fmaxf(hm, __shfl_xor(hm, off, 16));
  if (lane16 == 0) s_red[grp] = hm;
  __syncthreads();
  float fam = s_red[0];
#pragma unroll
  for (int cc = 1; cc < 8; ++cc) fam += s_red[cc];
  fam *= 0.125f;

  float eta = 2.5f / (1.0f + expf(-28.0f * (fam - 0.5f)));
  if (!(fam >= 0.2f)) eta = 0.0f;

  float v = eta * h;
  float vm = v;
#pragma unroll
  for (int off = 8; off >= 1; off >>= 1) vm = fmaxf(vm, __shfl_xor(vm, off, 16));
  float ee = expf(v - vm);
  float ss = ee;
#pragma unroll
  for (int off = 8; off >= 1; off >>= 1) ss += __shfl_xor(ss, off, 16);
  float p = ee / ss;

  uint32_t idx = (uint32_t)(((b * NM + m) * NCMS + grp) * NNEUR + lane16);
  float y = logf(p + 1e-30f) + gumbel_at(idx);

  float bv = y;
  int bi = lane16;
#pragma unroll
  for (int off = 8; off >= 1; off >>= 1) {
    float ov = __shfl_xor(bv, off, 16);
    int oi = __shfl_xor(bi, off, 16);
    if (ov > bv || (ov == bv && oi < bi)) { bv = ov; bi = oi; }
  }

  float act = (sums >= thr_min[m] && sums <= thr_max[m]) ? 1.0f : 0.0f;
  out[(size_t)(b * NM + m) * NOUT + tid] = (lane16 == bi) ? act : 0.0f;
}

// ---- fallback: round-0 single kernel (used only if d_ws is too small) ----
__global__ __launch_bounds__(128) void sparsey_fallback(
    const float* __restrict__ x, const float* __restrict__ w,
    const int* __restrict__ conns, const float* __restrict__ thr_min,
    const float* __restrict__ thr_max, float* __restrict__ out, int R) {
  const int tid = threadIdx.x;
  const int bid = blockIdx.x;
  const int m = bid >> 5;
  const int b = bid & 31;

  __shared__ int s_conn[RMAX];
  __shared__ unsigned char s_win[RMAX * 8];
  __shared__ float s_red[8];

  for (int r = tid; r < R; r += 128) s_conn[r] = conns[m * R + r];
  __syncthreads();

  const int grp = tid >> 4;
  const int lane16 = tid & 15;

  int nvalid = 0;
  const float* xb = x + (size_t)b * (NPM * NPF);
  for (int r = 0; r < R; ++r) {
    int pm = s_conn[r];
    if (pm == NPM) continue;
    ++nvalid;
    float xv = xb[(size_t)pm * NPF + tid];
    unsigned long long msk = __ballot(xv > 0.5f);
    int base = (tid & 63) & ~15;
    int wv = __builtin_ctzll((msk >> base) & 0xFFFFull);
    if (lane16 == 0) s_win[r * 8 + grp] = (unsigned char)wv;
  }
  __syncthreads();

  double acc = 0.0;
  const float* wm = w + (size_t)m * ((size_t)R * NPF * NOUT);
  for (int r = 0; r < R; ++r) {
    if (s_conn[r] == NPM) continue;
    const float* wr = wm + (size_t)r * (NPF * NOUT);
#pragma unroll
    for (int cm = 0; cm < 8; ++cm) {
      int row = cm * 16 + (int)s_win[r * 8 + cm];
      acc += (double)wr[row * NOUT + tid];
    }
  }

  float sums = 8.0f * (float)nvalid;
  float h = (float)acc / fmaxf(sums, 1.0f);

  float hm = h;
#pragma unroll
  for (int off = 8; off >= 1; off >>= 1) hm = fmaxf(hm, __shfl_xor(hm, off, 16));
  if (lane16 == 0) s_red[grp] = hm;
  __syncthreads();
  float fam = s_red[0];
#pragma unroll
  for (int c = 1; c < 8; ++c) fam += s_red[c];
  fam *= 0.125f;

  float eta = 2.5f / (1.0f + expf(-28.0f * (fam - 0.5f)));
  if (!(fam >= 0.2f)) eta = 0.0f;

  float v = eta * h;
  float vm = v;
#pragma unroll
  for (int off = 8; off >= 1; off >>= 1) vm = fmaxf(vm, __shfl_xor(vm, off, 16));
  float e = expf(v - vm);
  float ssum = e;
#pragma unroll
  for (int off = 8; off >= 1; off >>= 1) ssum += __shfl_xor(ssum, off, 16);
  float p = e / ssum;

  uint32_t idx = (uint32_t)(((b * NM + m) * NCMS + grp) * NNEUR + lane16);
  float y = logf(p + 1e-30f) + gumbel_at(idx);

  float bv = y;
  int bi = lane16;
#pragma unroll
  for (int off = 8; off >= 1; off >>= 1) {
    float ov = __shfl_xor(bv, off, 16);
    int oi = __shfl_xor(bi, off, 16);
    if (ov > bv || (ov == bv && oi < bi)) { bv = ov; bi = oi; }
  }

  float act = (sums >= thr_min[m] && sums <= thr_max[m]) ? 1.0f : 0.0f;
  out[(size_t)(b * NM + m) * NOUT + tid] = (lane16 == bi) ? act : 0.0f;
}

extern "C" void kernel_launch(void* const* d_in, const int* in_sizes, int n_in,
                              void* d_out, int out_size, void* d_ws, size_t ws_size,
                              hipStream_t stream) {
  const float* x = (const float*)d_in[0];
  const float* w = (const float*)d_in[1];
  const int* conns = (const int*)d_in[2];
  const float* tmin = (const float*)d_in[3];
  const float* tmax = (const float*)d_in[4];
  float* out = (float*)d_out;

  const int R = in_sizes[2] / NM;

  const size_t WIN_BYTES = 65536;  // 36864 used, pad to 64K for alignment
  const size_t PART_BYTES = (size_t)NC * NM * NB * NOUT * sizeof(float);

  if (ws_size < WIN_BYTES + PART_BYTES || R > RMAX || R > CLEN_MAX * NC) {
    sparsey_fallback<<<dim3(NM * NB), 128, 0, stream>>>(x, w, conns, tmin, tmax,
                                                        out, R);
    return;
  }

  unsigned char* win = (unsigned char*)d_ws;
  float* part = (float*)((char*)d_ws + WIN_BYTES);

  k_winners<<<dim3(NPM, 4), 128, 0, stream>>>(x, win);
  k_gather<<<dim3(NM * NC), 256, 0, stream>>>(w, conns, win, part, R);
  k_epilogue<<<dim3(NM * NB), 128, 0, stream>>>(part, conns, tmin, tmax, out, R);
}